// Round 17
// baseline (216.771 us; speedup 1.0000x reference)
//
#include <hip/hip_runtime.h>
#include <hip/hip_bf16.h>

// Problem: B=4, C=8, N=M=K=1024, DX=1.
// z1[b,c] = W_b (N x M) @ Z_{b,c} (M x K);  z2[b,c] = z1 @ z1^T (symmetric)
// W[b][n][m] = exp(-512 * (x[b][n] - xz[m])^2)
// d_out = [ xz (1024 f32) | z2 (4*8*1024*1024 f32) ]
// ws: W bf16 (8 MB) | Zt bf16 (64 MB) | z1 bf16 (64 MB)
//
// GEMM1: 256x256, 8 waves, BK=64, r9 register read-ahead (proven, ~80us).
// GEMM2 (THIS ROUND): 128x128 SYMM i<=j, 4 waves, BK=64, A-DIRECT:
//   A fragments loaded global->regs (skips LDS entirely: -50% LDS traffic,
//   -50% GLDS); B staged via GLDS involution, 3 slots x 16KB = 48KB ->
//   3 blocks/CU (launch_bounds(256,3); regs ~155 <= 170), 1152/768 = 1.5
//   rounds (fixes r16's 2.25-round quantization).
//   Ledger: per phase, compiler-inserted vmcnt before MFMA retires that
//   phase's A-loads; since A(t,kh0) is issued AFTER BG(t+1), the A-wait +
//   barrier transitively publishes B one tile ahead. Manual vmcnt(8)/(4)
//   guards are provable no-ops (documentation + safety).

typedef __attribute__((ext_vector_type(8))) unsigned short u16x8;
typedef __attribute__((ext_vector_type(8))) __bf16 bf16x8;
typedef __attribute__((ext_vector_type(4))) float f32x4;

typedef __attribute__((address_space(1))) void gvoid;
typedef __attribute__((address_space(3))) void svoid;
#define GLDS(g, s) __builtin_amdgcn_global_load_lds((gvoid*)(g), (svoid*)(s), 16, 0, 0)
#define BAR() asm volatile("s_barrier" ::: "memory")

__device__ __forceinline__ unsigned short f2bf(float f) {
  unsigned int u = __builtin_bit_cast(unsigned int, f);
  u += 0x7fffu + ((u >> 16) & 1u);   // round-to-nearest-even
  return (unsigned short)(u >> 16);
}

__device__ __forceinline__ bf16x8 as_bf16x8(u16x8 v) {
  return __builtin_bit_cast(bf16x8, v);
}

// ---------------- W = exp(-0.5*d^2/exp(2*ls)) as bf16 -----------------------
__global__ void weights_kernel(const float* __restrict__ xz, const float* __restrict__ x,
                               const float* __restrict__ ls, unsigned short* __restrict__ W) {
  int bn = blockIdx.x;
  float xv = x[bn];
  float coef = -0.5f * __expf(-2.0f * ls[0]);
  unsigned short* Wrow = W + (size_t)bn * 1024;
  #pragma unroll
  for (int i = 0; i < 4; ++i) {
    int m = threadIdx.x + i * 256;
    float d = xv - xz[m];
    Wrow[m] = f2bf(__expf(coef * d * d));
  }
}

// ---------------- Zt[b][c][k][m] = bf16(Z[b][c][m][k]) ----------------------
__global__ void transpose_kernel(const float* __restrict__ Z, unsigned short* __restrict__ Zt) {
  __shared__ float tile[64][65];
  int bc = blockIdx.z;
  const float* Zp = Z + ((size_t)bc << 20);
  unsigned short* Ztp = Zt + ((size_t)bc << 20);
  int m0 = blockIdx.x * 64, k0 = blockIdx.y * 64;
  int tx = threadIdx.x & 63, tg = threadIdx.x >> 6;
  #pragma unroll
  for (int i = 0; i < 16; ++i) {
    int ml = tg + i * 4;
    tile[ml][tx] = Zp[(size_t)(m0 + ml) * 1024 + k0 + tx];
  }
  __syncthreads();
  int tx2 = (threadIdx.x & 31) * 2, kg = threadIdx.x >> 5;
  #pragma unroll
  for (int i = 0; i < 8; ++i) {
    int kl = kg + i * 8;
    ushort2 v;
    v.x = f2bf(tile[tx2][kl]);
    v.y = f2bf(tile[tx2 + 1][kl]);
    *(ushort2*)&Ztp[(size_t)(k0 + kl) * 1024 + m0 + tx2] = v;
  }
}

// ---------------- GEMM1: z1 = W @ Zt^T (256x256, 8 waves, reg-pipelined) ----
template<bool A_PER_B>
__global__ __launch_bounds__(512, 2)
void gemm_nt8(const unsigned short* __restrict__ A, const unsigned short* __restrict__ B,
              unsigned short* __restrict__ Cbf) {
  extern __shared__ __align__(16) char smem[];   // 128 KB: A 2buf x 32KB @0, B @65536

  const int bid = blockIdx.x;
  const int w = ((bid & 7) << 6) + (bid >> 3);
  const int bc = w >> 4;
  const int t  = w & 15;
  const int bi = t & 3, bj = t >> 2;

  const unsigned short* Ap = A + ((size_t)(A_PER_B ? (bc >> 3) : bc) << 20);
  const unsigned short* Bp = B + ((size_t)bc << 20);
  const int tid = threadIdx.x;
  const int wv = tid >> 6, lane = tid & 63;
  const int wr = wv >> 2, wc = wv & 3;
  const int la = lane & 15, ha = lane >> 4;

  f32x4 acc[8][4] = {};

  const int slog = (lane & 7) ^ (lane >> 3);
  const int rloc = 2 * (lane >> 3) + (slog & 1);
  const int cloc = (slog >> 1) * 8;
  const unsigned short* gA0 = Ap + (size_t)(bi*256 +       wv*16 + rloc) * 1024 + cloc;
  const unsigned short* gA1 = Ap + (size_t)(bi*256 + 128 + wv*16 + rloc) * 1024 + cloc;
  const unsigned short* gB0 = Bp + (size_t)(bj*256 +       wv*16 + rloc) * 1024 + cloc;
  const unsigned short* gB1 = Bp + (size_t)(bj*256 + 128 + wv*16 + rloc) * 1024 + cloc;
  const int ldsw = wv * 1024;

  auto stageA = [&](int d, int kh, int kt) {
    const int ko = kt * 64 + kh * 32;
    char* dst = smem + d * 32768 + kh * 16384 + ldsw;
    GLDS(gA0 + ko, dst); GLDS(gA1 + ko, dst + 8192);
  };
  auto stageB = [&](int d, int kh, int kt) {
    const int ko = kt * 64 + kh * 32;
    char* dst = smem + 65536 + d * 32768 + kh * 16384 + ldsw;
    GLDS(gB0 + ko, dst); GLDS(gB1 + ko, dst + 8192);
  };

  const int sphys = ((ha << 1) | (la & 1)) ^ (la >> 1);
  const int abase = wr * 8192 + (la >> 1) * 128 + sphys * 16;
  const int bbase = 65536 + wc * 4096 + (la >> 1) * 128 + sphys * 16;

  u16x8 aX[4], aY[4], b0[4], b1[4];
  auto lda4 = [&](u16x8* dst, int d, int kh, int ms) {
    const char* p = smem + d * 32768 + kh * 16384 + ms * 4096 + abase;
    dst[0] = *(const u16x8*)(p);
    dst[1] = *(const u16x8*)(p + 1024);
    dst[2] = *(const u16x8*)(p + 2048);
    dst[3] = *(const u16x8*)(p + 3072);
  };
  auto ldb4 = [&](u16x8* dst, int d, int kh) {
    const char* p = smem + d * 32768 + kh * 16384 + bbase;
    dst[0] = *(const u16x8*)(p);
    dst[1] = *(const u16x8*)(p + 1024);
    dst[2] = *(const u16x8*)(p + 2048);
    dst[3] = *(const u16x8*)(p + 3072);
  };
  auto mfma16 = [&](const u16x8* Af, const u16x8* Bf, int ms) {
    #pragma unroll
    for (int i = 0; i < 4; ++i)
      #pragma unroll
      for (int n = 0; n < 4; ++n)
        acc[ms * 4 + i][n] = __builtin_amdgcn_mfma_f32_16x16x32_bf16(
            as_bf16x8(Af[i]), as_bf16x8(Bf[n]), acc[ms * 4 + i][n], 0, 0, 0);
  };

  stageA(0, 0, 0); stageB(0, 0, 0);
  stageA(0, 1, 0); stageB(0, 1, 0);
  stageA(1, 0, 1); stageB(1, 0, 1);
  asm volatile("s_waitcnt vmcnt(8)" ::: "memory");
  BAR();
  ldb4(b0, 0, 0); lda4(aX, 0, 0, 0);

  for (int tt = 0; tt < 14; ++tt) {
    const int d = tt & 1;
    stageA(d ^ 1, 1, tt + 1);
    lda4(aY, d, 0, 1);
    mfma16(aX, b0, 0);
    stageB(d ^ 1, 1, tt + 1);
    asm volatile("s_waitcnt vmcnt(8)" ::: "memory");
    BAR();
    ldb4(b1, d, 1); lda4(aX, d, 1, 0);
    mfma16(aY, b0, 1);
    stageA(d, 0, tt + 2);
    lda4(aY, d, 1, 1);
    mfma16(aX, b1, 0);
    stageB(d, 0, tt + 2);
    asm volatile("s_waitcnt vmcnt(8)" ::: "memory");
    BAR();
    ldb4(b0, d ^ 1, 0); lda4(aX, d ^ 1, 0, 0);
    mfma16(aY, b1, 1);
  }
  stageA(1, 1, 15);
  lda4(aY, 0, 0, 1);
  mfma16(aX, b0, 0);
  stageB(1, 1, 15);
  asm volatile("s_waitcnt vmcnt(8)" ::: "memory");
  BAR();
  ldb4(b1, 0, 1); lda4(aX, 0, 1, 0);
  mfma16(aY, b0, 1);
  lda4(aY, 0, 1, 1);
  mfma16(aX, b1, 0);
  asm volatile("s_waitcnt vmcnt(4)" ::: "memory");
  BAR();
  ldb4(b0, 1, 0); lda4(aX, 1, 0, 0);
  mfma16(aY, b1, 1);
  lda4(aY, 1, 0, 1);
  mfma16(aX, b0, 0);
  asm volatile("s_waitcnt vmcnt(0)" ::: "memory");
  BAR();
  ldb4(b1, 1, 1); lda4(aX, 1, 1, 0);
  mfma16(aY, b0, 1);
  lda4(aY, 1, 1, 1);
  mfma16(aX, b1, 0);
  mfma16(aY, b1, 1);
  BAR();

  const size_t cb20 = (size_t)bc << 20;
  unsigned short* sE = (unsigned short*)(smem) + wv * 1152;   // [16][72] per wave
  const int r2 = lane >> 2, ch = lane & 3;
  #pragma unroll
  for (int mb = 0; mb < 8; ++mb) {
    #pragma unroll
    for (int nb = 0; nb < 4; ++nb)
      #pragma unroll
      for (int j = 0; j < 4; ++j)
        sE[(ha * 4 + j) * 72 + nb * 16 + la] = f2bf(acc[mb][nb][j]);
    u16x8 v0 = *(const u16x8*)&sE[r2 * 72 + ch * 16];
    u16x8 v1 = *(const u16x8*)&sE[r2 * 72 + ch * 16 + 8];
    unsigned short* gp = Cbf + cb20 +
        (size_t)(bi * 256 + wr * 128 + mb * 16 + r2) * 1024 + bj * 256 + wc * 64 + ch * 16;
    *(u16x8*)gp = v0;
    *(u16x8*)(gp + 8) = v1;
  }
}

// ---------------- GEMM2: z2 = z1 z1^T (128x128 SYMM, A-direct, B-GLDS) -----
__global__ __launch_bounds__(256, 3)
void gemm2_sym(const unsigned short* __restrict__ A, float* __restrict__ Cf) {
  extern __shared__ __align__(16) char smem[];   // 48 KB: 3 slots x 16KB (B only)

  const int chunk = 144;                      // (36*32)/8
  int w = ((int)blockIdx.x & 7) * chunk + ((int)blockIdx.x >> 3);
  int bc = w / 36;
  int t  = w % 36;
  int bi = 0;
  while (t >= 8 - bi) { t -= 8 - bi; ++bi; }
  int bj = bi + t;                            // i <= j

  const unsigned short* Ap = A + ((size_t)bc << 20);
  const int tid = threadIdx.x;
  const int wave = tid >> 6, lane = tid & 63;
  const int wr = wave >> 1, wc = wave & 1;
  const int la = lane & 15, ha = lane >> 4;
  f32x4 acc[4][4] = {};

  // ---- B staging (involuted global source, linear LDS dest; 16-row regions)
  const int slog = (lane & 7) ^ (lane >> 3);
  const int rloc = 2 * (lane >> 3) + (slog & 1);
  const int cloc = (slog >> 1) * 8;
  const unsigned short* gB0 = Ap + (size_t)(bj*128 + (wave*2  )*16 + rloc)*1024 + cloc;
  const unsigned short* gB1 = Ap + (size_t)(bj*128 + (wave*2+1)*16 + rloc)*1024 + cloc;
  const int ldsw = wave * 2048;

  auto stageB = [&](int slot, int kt) {        // both k-halves: 4 GLDS
    const int ko = kt * 64;
    char* dst = smem + slot * 16384 + ldsw;
    GLDS(gB0 + ko,      dst);         GLDS(gB1 + ko,      dst + 1024);
    GLDS(gB0 + ko + 32, dst + 8192);  GLDS(gB1 + ko + 32, dst + 9216);
  };

  // ---- A direct from global (no LDS): frag m = rows bi*128+wr*64+m*16+la
  const unsigned short* aG = Ap + (size_t)(bi * 128 + wr * 64 + la) * 1024 + ha * 8;
  auto ldaG = [&](u16x8* dst, int kt, int kh) {
    const unsigned short* p = aG + kt * 64 + kh * 32;
    dst[0] = *(const u16x8*)(p);
    dst[1] = *(const u16x8*)(p + 16384);
    dst[2] = *(const u16x8*)(p + 32768);
    dst[3] = *(const u16x8*)(p + 49152);
  };

  const int sphys = ((ha << 1) | (la & 1)) ^ (la >> 1);
  const int inv = (la >> 1) * 128 + sphys * 16;
  auto ldbs = [&](u16x8* dst, int slot, int kh) {
    const char* p = smem + slot * 16384 + kh * 8192 + wc * 4096 + inv;
    dst[0] = *(const u16x8*)(p);
    dst[1] = *(const u16x8*)(p + 1024);
    dst[2] = *(const u16x8*)(p + 2048);
    dst[3] = *(const u16x8*)(p + 3072);
  };
  auto mfma16 = [&](const u16x8* Af, const u16x8* Bf) {
    __builtin_amdgcn_s_setprio(1);
    #pragma unroll
    for (int m = 0; m < 4; ++m)
      #pragma unroll
      for (int n = 0; n < 4; ++n)
        acc[m][n] = __builtin_amdgcn_mfma_f32_16x16x32_bf16(
            as_bf16x8(Af[m]), as_bf16x8(Bf[n]), acc[m][n], 0, 0, 0);
    __builtin_amdgcn_s_setprio(0);
  };

  u16x8 aX[4], aY[4], bX[4], bY[4];

  // prologue: BG(0):4, BG(1):4, A(0,kh0):4; vmcnt(8) retires BG(0); BAR; read
  stageB(0, 0);
  stageB(1, 1);
  ldaG(aX, 0, 0);
  asm volatile("s_waitcnt vmcnt(8)" ::: "memory");
  BAR();
  ldbs(bX, 0, 0);

  int c0 = 0, c1 = 1, c2 = 2;   // slots for tiles t, t+1, t+2
  for (int tt = 0; tt < 14; ++tt) {
    // phase kh0: stage BG(t+2); prefetch A(t,kh1); compute (t,kh0).
    // MFMA's compiler A-wait retires A(t,kh0) AND (older) BG(t+1).
    stageB(c2, tt + 2);
    ldaG(aY, tt, 1);
    mfma16(aX, bX);
    asm volatile("s_waitcnt vmcnt(8)" ::: "memory");   // no-op guard
    BAR();
    ldbs(bY, c0, 1);
    // phase kh1: prefetch A(t+1,kh0); compute (t,kh1).
    ldaG(aX, tt + 1, 0);
    mfma16(aY, bY);
    asm volatile("s_waitcnt vmcnt(8)" ::: "memory");   // no-op guard
    BAR();
    ldbs(bX, c1, 0);
    int tmp = c0; c0 = c1; c1 = c2; c2 = tmp;
  }
  // tt=14: no staging left. (c0,c1) = (2,0)
  ldaG(aY, 14, 1);
  mfma16(aX, bX);
  asm volatile("s_waitcnt vmcnt(4)" ::: "memory");
  BAR();
  ldbs(bY, c0, 1);
  ldaG(aX, 15, 0);
  mfma16(aY, bY);
  asm volatile("s_waitcnt vmcnt(4)" ::: "memory");
  BAR();
  ldbs(bX, c1, 0);
  // tt=15
  ldaG(aY, 15, 1);
  mfma16(aX, bX);
  asm volatile("s_waitcnt vmcnt(4)" ::: "memory");
  BAR();
  ldbs(bY, c1, 1);
  mfma16(aY, bY);
  asm volatile("s_waitcnt vmcnt(0)" ::: "memory");
  BAR();   // all K-loop LDS reads done before smem reuse

  const size_t cb20 = (size_t)bc << 20;

  // direct coalesced f32 write of the computed (upper) tile
  #pragma unroll
  for (int m = 0; m < 4; ++m) {
    int row0 = bi * 128 + wr * 64 + m * 16 + ha * 4;
    #pragma unroll
    for (int n = 0; n < 4; ++n) {
      int col = bj * 128 + wc * 64 + n * 16 + la;
      #pragma unroll
      for (int j = 0; j < 4; ++j)
        Cf[cb20 + (size_t)(row0 + j) * 1024 + col] = acc[m][n][j];
    }
  }
  if (bi != bj) {
    // mirror: LDS band transpose (32x128 f32 bands), coalesced f32x4 stores
    float (*sT)[129] = (float(*)[129])smem;   // 16.5 KB <= 48 KB
    #pragma unroll
    for (int b = 0; b < 4; ++b) {
      if (wr == (b >> 1)) {
        #pragma unroll
        for (int dm = 0; dm < 2; ++dm) {
          int m = (b & 1) * 2 + dm;
          #pragma unroll
          for (int n = 0; n < 4; ++n)
            #pragma unroll
            for (int j = 0; j < 4; ++j)
              sT[dm * 16 + ha * 4 + j][wc * 64 + n * 16 + la] = acc[m][n][j];
        }
      }
      __syncthreads();
      int c  = tid >> 1;
      int r0 = (tid & 1) * 16;
      float* gp = Cf + cb20 + (size_t)(bj * 128 + c) * 1024 + bi * 128 + b * 32 + r0;
      #pragma unroll
      for (int q = 0; q < 4; ++q) {
        f32x4 v;
        #pragma unroll
        for (int k = 0; k < 4; ++k) v[k] = sT[r0 + q * 4 + k][c];
        *(f32x4*)(gp + q * 4) = v;
      }
      __syncthreads();
    }
  }
}

extern "C" void kernel_launch(void* const* d_in, const int* in_sizes, int n_in,
                              void* d_out, int out_size, void* d_ws, size_t ws_size,
                              hipStream_t stream) {
  const float* xz = (const float*)d_in[0];
  const float* z  = (const float*)d_in[1];
  const float* x  = (const float*)d_in[2];
  const float* ls = (const float*)d_in[3];
  float* out = (float*)d_out;

  unsigned short* W  = (unsigned short*)d_ws;          // 8 MB
  unsigned short* Zt = W + ((size_t)4 << 20);          // 64 MB
  unsigned short* z1 = Zt + ((size_t)32 << 20);        // 64 MB

  hipFuncSetAttribute((const void*)gemm_nt8<true>,
                      hipFuncAttributeMaxDynamicSharedMemorySize, 131072);
  hipFuncSetAttribute((const void*)gemm2_sym,
                      hipFuncAttributeMaxDynamicSharedMemorySize, 49152);

  hipMemcpyAsync(out, xz, 1024 * sizeof(float), hipMemcpyDeviceToDevice, stream);
  weights_kernel<<<4096, 256, 0, stream>>>(xz, x, ls, W);
  transpose_kernel<<<dim3(16, 16, 32), 256, 0, stream>>>(z, Zt);
  gemm_nt8<true><<<512, 512, 131072, stream>>>(W, Zt, z1);
  gemm2_sym<<<32 * 36, 256, 49152, stream>>>(z1, out + 1024);
}

// Round 18
// 171.153 us; speedup vs baseline: 1.2665x; 1.2665x over previous
//
#include <hip/hip_runtime.h>
#include <hip/hip_bf16.h>

// Problem: B=4, C=8, N=M=K=1024, DX=1.
// z1[b,c] = W_b (N x M) @ Z_{b,c} (M x K);  z2[b,c] = z1 @ z1^T (symmetric)
// W[b][n][m] = exp(-512 * (x[b][n] - xz[m])^2)
// d_out = [ xz (1024 f32) | z2 (4*8*1024*1024 f32) ]
// ws: W bf16 (8 MB) | Zt bf16 (64 MB) | z1 bf16 (64 MB)
//
// FINAL (r15 revert — best measured 171.45us):
//   GEMM1 = 256x256, 8 waves, BK=64, register read-ahead, 2 barriers/K-tile,
//           counted vmcnt(8), involuted conflict-free LDS, no setprio.
//   GEMM2 = 128x128 SYMM i<=j, 4 waves, BK=32, 3-slot read-ahead,
//           counted vmcnt(4), setprio (3 blocks/CU regime), LDS-transpose
//           mirror epilogue.
// Failed-experiment ledger: 8-phase port (r11: -14%), 128x256 GEMM2
// (r13/r14: reg-file spill), BK=64 GEMM2 (r16: quantization-neutral),
// A-direct GEMM2 (r17: latency-exposed, -47%). Transpose & weights at HBM
// roofline. LDS-read volume ~= MFMA time at this shape -> practical plateau.

typedef __attribute__((ext_vector_type(8))) unsigned short u16x8;
typedef __attribute__((ext_vector_type(8))) __bf16 bf16x8;
typedef __attribute__((ext_vector_type(4))) float f32x4;

typedef __attribute__((address_space(1))) void gvoid;
typedef __attribute__((address_space(3))) void svoid;
#define GLDS(g, s) __builtin_amdgcn_global_load_lds((gvoid*)(g), (svoid*)(s), 16, 0, 0)
#define BAR() asm volatile("s_barrier" ::: "memory")

__device__ __forceinline__ unsigned short f2bf(float f) {
  unsigned int u = __builtin_bit_cast(unsigned int, f);
  u += 0x7fffu + ((u >> 16) & 1u);   // round-to-nearest-even
  return (unsigned short)(u >> 16);
}

__device__ __forceinline__ bf16x8 as_bf16x8(u16x8 v) {
  return __builtin_bit_cast(bf16x8, v);
}

// ---------------- W = exp(-0.5*d^2/exp(2*ls)) as bf16 -----------------------
__global__ void weights_kernel(const float* __restrict__ xz, const float* __restrict__ x,
                               const float* __restrict__ ls, unsigned short* __restrict__ W) {
  int bn = blockIdx.x;
  float xv = x[bn];
  float coef = -0.5f * __expf(-2.0f * ls[0]);
  unsigned short* Wrow = W + (size_t)bn * 1024;
  #pragma unroll
  for (int i = 0; i < 4; ++i) {
    int m = threadIdx.x + i * 256;
    float d = xv - xz[m];
    Wrow[m] = f2bf(__expf(coef * d * d));
  }
}

// ---------------- Zt[b][c][k][m] = bf16(Z[b][c][m][k]) ----------------------
__global__ void transpose_kernel(const float* __restrict__ Z, unsigned short* __restrict__ Zt) {
  __shared__ float tile[64][65];
  int bc = blockIdx.z;
  const float* Zp = Z + ((size_t)bc << 20);
  unsigned short* Ztp = Zt + ((size_t)bc << 20);
  int m0 = blockIdx.x * 64, k0 = blockIdx.y * 64;
  int tx = threadIdx.x & 63, tg = threadIdx.x >> 6;
  #pragma unroll
  for (int i = 0; i < 16; ++i) {
    int ml = tg + i * 4;
    tile[ml][tx] = Zp[(size_t)(m0 + ml) * 1024 + k0 + tx];
  }
  __syncthreads();
  int tx2 = (threadIdx.x & 31) * 2, kg = threadIdx.x >> 5;
  #pragma unroll
  for (int i = 0; i < 8; ++i) {
    int kl = kg + i * 8;
    ushort2 v;
    v.x = f2bf(tile[tx2][kl]);
    v.y = f2bf(tile[tx2 + 1][kl]);
    *(ushort2*)&Ztp[(size_t)(k0 + kl) * 1024 + m0 + tx2] = v;
  }
}

// ---------------- GEMM1: z1 = W @ Zt^T (256x256, 8 waves, reg-pipelined) ----
template<bool A_PER_B>
__global__ __launch_bounds__(512, 2)
void gemm_nt8(const unsigned short* __restrict__ A, const unsigned short* __restrict__ B,
              unsigned short* __restrict__ Cbf) {
  extern __shared__ __align__(16) char smem[];   // 128 KB: A 2buf x 32KB @0, B @65536

  const int bid = blockIdx.x;
  const int w = ((bid & 7) << 6) + (bid >> 3);
  const int bc = w >> 4;
  const int t  = w & 15;
  const int bi = t & 3, bj = t >> 2;

  const unsigned short* Ap = A + ((size_t)(A_PER_B ? (bc >> 3) : bc) << 20);
  const unsigned short* Bp = B + ((size_t)bc << 20);
  const int tid = threadIdx.x;
  const int wv = tid >> 6, lane = tid & 63;
  const int wr = wv >> 2, wc = wv & 3;
  const int la = lane & 15, ha = lane >> 4;

  f32x4 acc[8][4] = {};

  const int slog = (lane & 7) ^ (lane >> 3);
  const int rloc = 2 * (lane >> 3) + (slog & 1);
  const int cloc = (slog >> 1) * 8;
  const unsigned short* gA0 = Ap + (size_t)(bi*256 +       wv*16 + rloc) * 1024 + cloc;
  const unsigned short* gA1 = Ap + (size_t)(bi*256 + 128 + wv*16 + rloc) * 1024 + cloc;
  const unsigned short* gB0 = Bp + (size_t)(bj*256 +       wv*16 + rloc) * 1024 + cloc;
  const unsigned short* gB1 = Bp + (size_t)(bj*256 + 128 + wv*16 + rloc) * 1024 + cloc;
  const int ldsw = wv * 1024;

  auto stageA = [&](int d, int kh, int kt) {
    const int ko = kt * 64 + kh * 32;
    char* dst = smem + d * 32768 + kh * 16384 + ldsw;
    GLDS(gA0 + ko, dst); GLDS(gA1 + ko, dst + 8192);
  };
  auto stageB = [&](int d, int kh, int kt) {
    const int ko = kt * 64 + kh * 32;
    char* dst = smem + 65536 + d * 32768 + kh * 16384 + ldsw;
    GLDS(gB0 + ko, dst); GLDS(gB1 + ko, dst + 8192);
  };

  const int sphys = ((ha << 1) | (la & 1)) ^ (la >> 1);
  const int abase = wr * 8192 + (la >> 1) * 128 + sphys * 16;
  const int bbase = 65536 + wc * 4096 + (la >> 1) * 128 + sphys * 16;

  u16x8 aX[4], aY[4], b0[4], b1[4];
  auto lda4 = [&](u16x8* dst, int d, int kh, int ms) {
    const char* p = smem + d * 32768 + kh * 16384 + ms * 4096 + abase;
    dst[0] = *(const u16x8*)(p);
    dst[1] = *(const u16x8*)(p + 1024);
    dst[2] = *(const u16x8*)(p + 2048);
    dst[3] = *(const u16x8*)(p + 3072);
  };
  auto ldb4 = [&](u16x8* dst, int d, int kh) {
    const char* p = smem + d * 32768 + kh * 16384 + bbase;
    dst[0] = *(const u16x8*)(p);
    dst[1] = *(const u16x8*)(p + 1024);
    dst[2] = *(const u16x8*)(p + 2048);
    dst[3] = *(const u16x8*)(p + 3072);
  };
  auto mfma16 = [&](const u16x8* Af, const u16x8* Bf, int ms) {
    #pragma unroll
    for (int i = 0; i < 4; ++i)
      #pragma unroll
      for (int n = 0; n < 4; ++n)
        acc[ms * 4 + i][n] = __builtin_amdgcn_mfma_f32_16x16x32_bf16(
            as_bf16x8(Af[i]), as_bf16x8(Bf[n]), acc[ms * 4 + i][n], 0, 0, 0);
  };

  stageA(0, 0, 0); stageB(0, 0, 0);
  stageA(0, 1, 0); stageB(0, 1, 0);
  stageA(1, 0, 1); stageB(1, 0, 1);
  asm volatile("s_waitcnt vmcnt(8)" ::: "memory");
  BAR();
  ldb4(b0, 0, 0); lda4(aX, 0, 0, 0);

  for (int tt = 0; tt < 14; ++tt) {
    const int d = tt & 1;
    stageA(d ^ 1, 1, tt + 1);
    lda4(aY, d, 0, 1);
    mfma16(aX, b0, 0);
    stageB(d ^ 1, 1, tt + 1);
    asm volatile("s_waitcnt vmcnt(8)" ::: "memory");
    BAR();
    ldb4(b1, d, 1); lda4(aX, d, 1, 0);
    mfma16(aY, b0, 1);
    stageA(d, 0, tt + 2);
    lda4(aY, d, 1, 1);
    mfma16(aX, b1, 0);
    stageB(d, 0, tt + 2);
    asm volatile("s_waitcnt vmcnt(8)" ::: "memory");
    BAR();
    ldb4(b0, d ^ 1, 0); lda4(aX, d ^ 1, 0, 0);
    mfma16(aY, b1, 1);
  }
  stageA(1, 1, 15);
  lda4(aY, 0, 0, 1);
  mfma16(aX, b0, 0);
  stageB(1, 1, 15);
  asm volatile("s_waitcnt vmcnt(8)" ::: "memory");
  BAR();
  ldb4(b1, 0, 1); lda4(aX, 0, 1, 0);
  mfma16(aY, b0, 1);
  lda4(aY, 0, 1, 1);
  mfma16(aX, b1, 0);
  asm volatile("s_waitcnt vmcnt(4)" ::: "memory");
  BAR();
  ldb4(b0, 1, 0); lda4(aX, 1, 0, 0);
  mfma16(aY, b1, 1);
  lda4(aY, 1, 0, 1);
  mfma16(aX, b0, 0);
  asm volatile("s_waitcnt vmcnt(0)" ::: "memory");
  BAR();
  ldb4(b1, 1, 1); lda4(aX, 1, 1, 0);
  mfma16(aY, b0, 1);
  lda4(aY, 1, 1, 1);
  mfma16(aX, b1, 0);
  mfma16(aY, b1, 1);
  BAR();

  const size_t cb20 = (size_t)bc << 20;
  unsigned short* sE = (unsigned short*)(smem) + wv * 1152;   // [16][72] per wave
  const int r2 = lane >> 2, ch = lane & 3;
  #pragma unroll
  for (int mb = 0; mb < 8; ++mb) {
    #pragma unroll
    for (int nb = 0; nb < 4; ++nb)
      #pragma unroll
      for (int j = 0; j < 4; ++j)
        sE[(ha * 4 + j) * 72 + nb * 16 + la] = f2bf(acc[mb][nb][j]);
    u16x8 v0 = *(const u16x8*)&sE[r2 * 72 + ch * 16];
    u16x8 v1 = *(const u16x8*)&sE[r2 * 72 + ch * 16 + 8];
    unsigned short* gp = Cbf + cb20 +
        (size_t)(bi * 256 + wr * 128 + mb * 16 + r2) * 1024 + bj * 256 + wc * 64 + ch * 16;
    *(u16x8*)gp = v0;
    *(u16x8*)(gp + 8) = v1;
  }
}

// ---------------- GEMM2: z2 = z1 z1^T (128x128 SYMM, read-ahead pipeline) ---
// 3 slots, stage-3-ahead; read tile t+1 frags during tile t MFMA;
// vmcnt(4)+BAR per tile retires tile t+2 (publication leads reads by 1).
__global__ __launch_bounds__(256, 3)
void gemm2_sym(const unsigned short* __restrict__ A, float* __restrict__ Cf) {
  __shared__ __align__(16) char smem[49152];  // A: 3 x 8KB @0, B: 3 x 8KB @24576

  const int chunk = 144;                      // (36*32)/8
  int w = ((int)blockIdx.x & 7) * chunk + ((int)blockIdx.x >> 3);
  int bc = w / 36;
  int t  = w % 36;
  int bi = 0;
  while (t >= 8 - bi) { t -= 8 - bi; ++bi; }
  int bj = bi + t;                            // i <= j

  const unsigned short* Ap = A + ((size_t)bc << 20);
  const int tid = threadIdx.x;
  const int wave = tid >> 6, lane = tid & 63;
  const int wr = wave >> 1, wc = wave & 1;
  const int la = lane & 15, ha = lane >> 4;
  f32x4 acc[4][4] = {};

  // staging source (pre-swizzled global address; LDS dest stays linear)
  const int slog = (lane & 7) ^ ((lane >> 3) & 7);
  const int rloc = 2 * (lane >> 3) + (slog & 1);
  const int cloc = (slog >> 1) * 8;
  const unsigned short* gA0 = Ap + (size_t)(bi * 128 + (wave * 2)     * 16 + rloc) * 1024 + cloc;
  const unsigned short* gA1 = Ap + (size_t)(bi * 128 + (wave * 2 + 1) * 16 + rloc) * 1024 + cloc;
  const unsigned short* gB0 = Ap + (size_t)(bj * 128 + (wave * 2)     * 16 + rloc) * 1024 + cloc;
  const unsigned short* gB1 = Ap + (size_t)(bj * 128 + (wave * 2 + 1) * 16 + rloc) * 1024 + cloc;

  auto stage = [&](int slot, int kt) {
    char* dA = smem + slot * 8192 + wave * 2048;
    char* dB = smem + 24576 + slot * 8192 + wave * 2048;
    GLDS(gA0 + kt, dA); GLDS(gA1 + kt, dA + 1024);
    GLDS(gB0 + kt, dB); GLDS(gB1 + kt, dB + 1024);
  };

  const int sphys = ((ha << 1) | (la & 1)) ^ (la >> 1);
  const int aoff = wr * 4096 + (la >> 1) * 128 + sphys * 16;
  const int boff = 24576 + wc * 4096 + (la >> 1) * 128 + sphys * 16;

  u16x8 aX[4], bX[4], aY[4], bY[4];
  auto rd = [&](u16x8* da, u16x8* db, int slot) {
    const char* pa = smem + slot * 8192 + aoff;
    const char* pb = smem + slot * 8192 + boff;
    da[0] = *(const u16x8*)(pa);
    da[1] = *(const u16x8*)(pa + 1024);
    da[2] = *(const u16x8*)(pa + 2048);
    da[3] = *(const u16x8*)(pa + 3072);
    db[0] = *(const u16x8*)(pb);
    db[1] = *(const u16x8*)(pb + 1024);
    db[2] = *(const u16x8*)(pb + 2048);
    db[3] = *(const u16x8*)(pb + 3072);
  };
  auto mfma16 = [&](const u16x8* Af, const u16x8* Bf) {
    __builtin_amdgcn_s_setprio(1);
    #pragma unroll
    for (int m = 0; m < 4; ++m)
      #pragma unroll
      for (int n = 0; n < 4; ++n)
        acc[m][n] = __builtin_amdgcn_mfma_f32_16x16x32_bf16(
            as_bf16x8(Af[m]), as_bf16x8(Bf[n]), acc[m][n], 0, 0, 0);
    __builtin_amdgcn_s_setprio(0);
  };

  // prologue: tiles 0,1,2 staged (12 GLDS); vmcnt(4) retires tiles 0,1; BAR;
  // read tile0 frags; lgkmcnt(0)+BAR so iter-0 restage of slot0 is WAR-safe.
  stage(0, 0); stage(1, 32); stage(2, 64);
  asm volatile("s_waitcnt vmcnt(4)" ::: "memory");
  BAR();
  rd(aX, bX, 0);
  asm volatile("s_waitcnt lgkmcnt(0)" ::: "memory");
  BAR();

  int p0 = 0, p1 = 1, p2 = 2;   // slots: stage=t%3, read=(t+1)%3, spare
  for (int t2 = 0; t2 < 28; t2 += 2) {
    // even tile (cur=X)
    stage(p0, (t2 + 3) * 32);
    rd(aY, bY, p1);
    mfma16(aX, bX);
    asm volatile("s_waitcnt vmcnt(4)" ::: "memory");
    BAR();
    // odd tile (cur=Y)
    stage(p1, (t2 + 4) * 32);
    rd(aX, bX, p2);
    mfma16(aY, bY);
    asm volatile("s_waitcnt vmcnt(4)" ::: "memory");
    BAR();
    int tmp = p2; p2 = p1; p1 = p0; p0 = tmp;
  }
  // t=28 (cur=X): stage tile 31
  stage(p0, 31 * 32);
  rd(aY, bY, p1);              // tile 29
  mfma16(aX, bX);              // tile 28
  asm volatile("s_waitcnt vmcnt(4)" ::: "memory");   // retires tile 30
  BAR();
  // t=29 (cur=Y)
  rd(aX, bX, p2);              // tile 30
  mfma16(aY, bY);              // tile 29
  asm volatile("s_waitcnt vmcnt(0)" ::: "memory");   // retires tile 31
  BAR();
  // t=30 (cur=X)
  rd(aY, bY, p0);              // tile 31
  mfma16(aX, bX);              // tile 30
  // t=31
  mfma16(aY, bY);              // tile 31
  BAR();   // all K-loop LDS reads done before smem reuse

  const size_t cb20 = (size_t)bc << 20;

  // direct coalesced f32 write of the computed (upper) tile
  #pragma unroll
  for (int m = 0; m < 4; ++m) {
    int row0 = bi * 128 + wr * 64 + m * 16 + ha * 4;
    #pragma unroll
    for (int n = 0; n < 4; ++n) {
      int col = bj * 128 + wc * 64 + n * 16 + la;
      #pragma unroll
      for (int j = 0; j < 4; ++j)
        Cf[cb20 + (size_t)(row0 + j) * 1024 + col] = acc[m][n][j];
    }
  }
  if (bi != bj) {
    // mirror: LDS band transpose (32x128 f32 bands), coalesced f32x4 stores
    float (*sT)[129] = (float(*)[129])smem;
    #pragma unroll
    for (int b = 0; b < 4; ++b) {
      if (wr == (b >> 1)) {
        #pragma unroll
        for (int dm = 0; dm < 2; ++dm) {
          int m = (b & 1) * 2 + dm;
          #pragma unroll
          for (int n = 0; n < 4; ++n)
            #pragma unroll
            for (int j = 0; j < 4; ++j)
              sT[dm * 16 + ha * 4 + j][wc * 64 + n * 16 + la] = acc[m][n][j];
        }
      }
      __syncthreads();
      int c  = tid >> 1;
      int r0 = (tid & 1) * 16;
      float* gp = Cf + cb20 + (size_t)(bj * 128 + c) * 1024 + bi * 128 + b * 32 + r0;
      #pragma unroll
      for (int q = 0; q < 4; ++q) {
        f32x4 v;
        #pragma unroll
        for (int k = 0; k < 4; ++k) v[k] = sT[r0 + q * 4 + k][c];
        *(f32x4*)(gp + q * 4) = v;
      }
      __syncthreads();
    }
  }
}

extern "C" void kernel_launch(void* const* d_in, const int* in_sizes, int n_in,
                              void* d_out, int out_size, void* d_ws, size_t ws_size,
                              hipStream_t stream) {
  const float* xz = (const float*)d_in[0];
  const float* z  = (const float*)d_in[1];
  const float* x  = (const float*)d_in[2];
  const float* ls = (const float*)d_in[3];
  float* out = (float*)d_out;

  unsigned short* W  = (unsigned short*)d_ws;          // 8 MB
  unsigned short* Zt = W + ((size_t)4 << 20);          // 64 MB
  unsigned short* z1 = Zt + ((size_t)32 << 20);        // 64 MB

  hipFuncSetAttribute((const void*)gemm_nt8<true>,
                      hipFuncAttributeMaxDynamicSharedMemorySize, 131072);

  hipMemcpyAsync(out, xz, 1024 * sizeof(float), hipMemcpyDeviceToDevice, stream);
  weights_kernel<<<4096, 256, 0, stream>>>(xz, x, ls, W);
  transpose_kernel<<<dim3(16, 16, 32), 256, 0, stream>>>(z, Zt);
  gemm_nt8<true><<<512, 512, 131072, stream>>>(W, Zt, z1);
  gemm2_sym<<<32 * 36, 256, 0, stream>>>(z1, out + 1024);
}